// Round 3
// baseline (145.056 us; speedup 1.0000x reference)
//
#include <hip/hip_runtime.h>
#include <math.h>

#define N 8192
#define BIT 32
#define NCLASS 100
#define ALPHA 0.1
#define BEITA 1.0
#define GAMMA 0.1

#define BT 128                      // block tile (128x128 output per block)
#define NT (N / BT)                 // 64 tile-rows
#define NPAIRBLK (NT * (NT + 1) / 2)

typedef __attribute__((ext_vector_type(8))) short s16x8;   // 8 bf16 (4 VGPRs)
typedef __attribute__((ext_vector_type(4))) float f32x4;   // MFMA accum

// round-to-nearest-even fp32 -> bf16 bits
static __device__ __forceinline__ unsigned short f2bf(float f) {
    unsigned int x = __float_as_uint(f);
    x += 0x7fff + ((x >> 16) & 1);
    return (unsigned short)(x >> 16);
}

// ws layout (bytes):
//   [0..255]     double acc[32]: [0..7]=pair slots, [8..15]=cls, [16..23]=m2, [24..31]=bal
//   [256..655]   int counts[NCLASS]
//   [656..659]   int cnt (pair-block ticket)
//   [1024..33791]   int labels[N]
//   [33792..558k]   ushort ub[N*BIT]  (bf16 copy of u)

// ---------------- fused prep: labels + histogram + cls loss + quant/bal + bf16 cast ----
__global__ __launch_bounds__(256) void prep_kernel(
    const float* __restrict__ u, const float* __restrict__ Y, const float* __restrict__ y,
    int* __restrict__ labels, int* __restrict__ counts,
    unsigned short* __restrict__ ub, double* __restrict__ acc)
{
    const int t = threadIdx.x;
    const int lane = t & 63;
    const int w = t >> 6;
    const int row0 = blockIdx.x * 32;            // block owns 32 rows

    // ---- cls + labels: wave w handles rows row0 + w*8 .. +7
    float wcls = 0.f;
    #pragma unroll 1
    for (int rr = 0; rr < 8; ++rr) {
        const int r = row0 + w * 8 + rr;
        const float* Yp = Y + (size_t)r * NCLASS;
        const float* yp = y + (size_t)r * NCLASS;
        const bool has2 = lane < (NCLASS - 64);
        float Y0 = Yp[lane];
        float Y1 = has2 ? Yp[64 + lane] : -1e30f;
        float y0 = yp[lane];
        float y1 = has2 ? yp[64 + lane] : 0.f;
        float m = fmaxf(Y0, Y1);
        #pragma unroll
        for (int o = 32; o; o >>= 1) m = fmaxf(m, __shfl_xor(m, o, 64));
        float e  = __expf(Y0 - m) + (has2 ? __expf(Y1 - m) : 0.f);
        float tg = y0 * Y0 + (has2 ? y1 * Y1 : 0.f);
        #pragma unroll
        for (int o = 32; o; o >>= 1) { e += __shfl_xor(e, o, 64); tg += __shfl_xor(tg, o, 64); }
        unsigned long long b0 = __ballot(y0 > 0.5f);
        unsigned long long b1 = __ballot(has2 && (y1 > 0.5f));
        if (lane == 0) {
            int lbl = b0 ? (__ffsll((long long)b0) - 1) : (64 + __ffsll((long long)b1) - 1);
            labels[r] = lbl;
            atomicAdd(&counts[lbl], 1);
            wcls += m + __logf(e) - tg;
        }
    }

    // ---- u: quant + bal + bf16 cast. thread t owns floats [t*4, t*4+4) of block's 1024-chunk
    const float4 v = *(const float4*)(u + (size_t)row0 * BIT + t * 4);
    float rs = v.x + v.y + v.z + v.w;
    float bal = 0.f;
    {
        float vv[4] = {v.x, v.y, v.z, v.w};
        #pragma unroll
        for (int j = 0; j < 4; ++j) {
            float x = vv[j];
            float bb = (x > 0.f) ? 1.f : ((x < 0.f) ? -1.f : 0.f);  // jnp.sign
            float d = x - bb;
            bal = fmaf(d, d, bal);
        }
        ushort4 c;
        c.x = f2bf(v.x); c.y = f2bf(v.y); c.z = f2bf(v.z); c.w = f2bf(v.w);
        *(ushort4*)(ub + (size_t)row0 * BIT + t * 4) = c;
    }
    #pragma unroll
    for (int o = 1; o < 8; o <<= 1) rs += __shfl_xor(rs, o, 64);   // 8 lanes = one u row
    float mrow = rs * (1.f / BIT);
    float m2 = ((t & 7) == 0) ? mrow * mrow : 0.f;
    #pragma unroll
    for (int o = 32; o; o >>= 1) { m2 += __shfl_down(m2, o, 64); bal += __shfl_down(bal, o, 64); }

    __shared__ double red[4][3];
    if (lane == 0) { red[w][0] = (double)wcls; red[w][1] = (double)m2; red[w][2] = (double)bal; }
    __syncthreads();
    if (t == 0) {
        const int slot = blockIdx.x & 7;
        atomicAdd(&acc[8 + slot],  red[0][0] + red[1][0] + red[2][0] + red[3][0]);
        atomicAdd(&acc[16 + slot], red[0][1] + red[1][1] + red[2][1] + red[3][1]);
        atomicAdd(&acc[24 + slot], red[0][2] + red[1][2] + red[2][2] + red[3][2]);
    }
}

// ---------------- pairwise hash loss: bf16 MFMA, triangular grid, ticket finalize -------
__global__ __launch_bounds__(256, 3) void pair_kernel(
    const unsigned short* __restrict__ ub, const int* __restrict__ labels,
    const int* __restrict__ counts, double* __restrict__ acc,
    int* __restrict__ cnt, float* __restrict__ out)
{
    // decode triangular block index -> (ti, tj), ti <= tj
    int b = blockIdx.x;
    int ti = 0;
    while (b >= NT - ti) { b -= NT - ti; ++ti; }
    const int tj = ti + b;
    const int i0 = ti * BT, j0 = tj * BT;

    __shared__ __align__(16) unsigned short Us[4][256][8];   // 16 KB
    __shared__ int Ls[256];
    __shared__ float wred[4];

    const int t = threadIdx.x;

    // stage: thread t owns staged row t (0..127 = A rows i0.., 128..255 = B rows j0..)
    {
        const int g = (t < BT) ? (i0 + t) : (j0 + t - BT);
        const s16x8* p = (const s16x8*)(ub + (size_t)g * BIT);
        #pragma unroll
        for (int c = 0; c < 4; ++c) *(s16x8*)&Us[c][t][0] = p[c];
        Ls[t] = labels[g];
    }

    // per-block scales (uniform scalar work, overlaps staging)
    double simsum = 0.0;
    for (int c = 0; c < NCLASS; ++c) { double v = (double)counts[c]; simsum += v * v; }
    double s1 = simsum - (double)N;
    double s0 = (double)N * (double)N - simsum;
    if (s0 == 0.0) s0 = 1.0;
    if (s1 == 0.0) s1 = 1.0;
    const float spos = (float)((s0 + s1) / s1);
    const float sneg = (float)((s0 + s1) / s0);

    __syncthreads();

    const int w = t >> 6;                 // wave 0..3, 2x2 wave grid, 64x64 per wave
    const int wy = w >> 1, wx = w & 1;
    const int lane = t & 63;
    const int quad = lane >> 4, lr = lane & 15;

    s16x8 av[4], bv[4];
    #pragma unroll
    for (int x = 0; x < 4; ++x) {
        av[x] = *(const s16x8*)&Us[quad][wy * 64 + x * 16 + lr][0];
        bv[x] = *(const s16x8*)&Us[quad][128 + wx * 64 + x * 16 + lr][0];
    }

    f32x4 accf[4][4];
    #pragma unroll
    for (int a = 0; a < 4; ++a)
        #pragma unroll
        for (int c = 0; c < 4; ++c)
            accf[a][c] = __builtin_amdgcn_mfma_f32_16x16x32_bf16(
                av[a], bv[c], (f32x4){0.f, 0.f, 0.f, 0.f}, 0, 0, 0);

    int lbv[4], lav[16];
    #pragma unroll
    for (int c = 0; c < 4; ++c) lbv[c] = Ls[128 + wx * 64 + c * 16 + lr];
    #pragma unroll
    for (int a = 0; a < 4; ++a)
        #pragma unroll
        for (int r = 0; r < 4; ++r) lav[a * 4 + r] = Ls[wy * 64 + a * 16 + quad * 4 + r];

    float sum = 0.f;
    #pragma unroll
    for (int a = 0; a < 4; ++a) {
        #pragma unroll
        for (int r = 0; r < 4; ++r) {
            const int gi = i0 + wy * 64 + a * 16 + quad * 4 + r;
            const int la = lav[a * 4 + r];
            #pragma unroll
            for (int c = 0; c < 4; ++c) {
                const int gj = j0 + wx * 64 + c * 16 + lr;
                float th = 0.5f * accf[a][c][r];      // C/D: col=lane&15, row=quad*4+reg
                float e = __expf(-fabsf(th));
                float lg = __logf(1.f + e);
                bool sim = (la == lbv[c]);
                float base = sim ? fmaxf(-th, 0.f) : fmaxf(th, 0.f);
                float sc = sim ? spos : sneg;
                sc = (gj > gi) ? sc : 0.f;            // strict upper triangle
                sum = fmaf(base + lg, sc, sum);
            }
        }
    }

    #pragma unroll
    for (int o = 32; o; o >>= 1) sum += __shfl_down(sum, o, 64);
    if (lane == 0) wred[w] = sum;
    __syncthreads();
    if (t == 0) {
        atomicAdd(&acc[blockIdx.x & 7], (double)(wred[0] + wred[1] + wred[2] + wred[3]));
        __threadfence();
        int old = atomicAdd(cnt, 1);
        if (old == NPAIRBLK - 1) {                    // last block finalizes
            double a0 = 0, a1 = 0, a2 = 0, a3 = 0;
            for (int s = 0; s < 8; ++s) {
                a0 += atomicAdd(&acc[s], 0.0);
                a1 += atomicAdd(&acc[8 + s], 0.0);
                a2 += atomicAdd(&acc[16 + s], 0.0);
                a3 += atomicAdd(&acc[24 + s], 0.0);
            }
            double lik   = 2.0 * a0 / ((double)N * (double)(N - 1));
            double cls   = a1 / (double)N;
            double quant = ALPHA * (a2 / (double)N);
            double bal   = GAMMA * (a3 / ((double)N * (double)BIT));
            out[0] = (float)(lik + BEITA * cls + quant + bal);
        }
    }
}

extern "C" void kernel_launch(void* const* d_in, const int* in_sizes, int n_in,
                              void* d_out, int out_size, void* d_ws, size_t ws_size,
                              hipStream_t stream) {
    const float* u = (const float*)d_in[0];   // [N, BIT]
    const float* Y = (const float*)d_in[1];   // [N, NCLASS]
    const float* y = (const float*)d_in[2];   // [N, NCLASS] one-hot
    float* out = (float*)d_out;

    char* ws = (char*)d_ws;
    double* acc    = (double*)(ws + 0);       // 32 doubles
    int*    counts = (int*)(ws + 256);
    int*    cnt    = (int*)(ws + 656);
    int*    labels = (int*)(ws + 1024);
    unsigned short* ub = (unsigned short*)(ws + 33792);

    hipMemsetAsync(d_ws, 0, 704, stream);     // zero acc + counts + ticket
    prep_kernel<<<N / 32, 256, 0, stream>>>(u, Y, y, labels, counts, ub, acc);
    pair_kernel<<<NPAIRBLK, 256, 0, stream>>>(ub, labels, counts, acc, cnt, out);
}